// Round 7
// baseline (2060.881 us; speedup 1.0000x reference)
//
#include <hip/hip_runtime.h>
#include <hip/hip_bf16.h>
#include <math.h>

// ---------------------------------------------------------------------------
// Adaptive-softmax NLL, MI355X.
// r7: LSE GEMMs in pure bf16 (NP=1), adapt projections in bf16x3 (NP=3).
// XCD sharding fixed: ROWSHARD for head/adapt (A L2-resident per XCD),
// COLSHARD for compacted tails (B-shard resident). global_load_lds staging.
// Fallback (small ws): fp32 vector-FMA path.
// ---------------------------------------------------------------------------

#define CUT1 20000
#define CUT2 40000
#define NTOK 50257
#define DIM  1024
#define P1   341
#define P2   113
#define XT1_LD 384
#define XT2_LD 128

#define VPAD0 20096   // head vocab 20002 -> 157 tiles of 128
#define VPAD1 20096   // tail1 vocab 20000
#define VPAD2 10368   // tail2 vocab 10257 -> 81 tiles
#define K1P   352     // tail1 K 341 -> 11 steps of 32
#define K2P   128     // tail2 K 113 -> 4 steps
#define A1R   384     // adapt1 padded out-dim
#define A2R   128

typedef unsigned short u16;
typedef __attribute__((ext_vector_type(8))) short short8;
typedef __attribute__((ext_vector_type(4))) float f32x4;

typedef __attribute__((address_space(1))) const unsigned int gu32;
typedef __attribute__((address_space(3))) unsigned int su32;

__device__ __forceinline__ void gload16(const u16* g, u16* s) {
  __builtin_amdgcn_global_load_lds((gu32*)g, (su32*)s, 16, 0, 0);
}

// Online-logsumexp merge of (m,s) into packed {s:hi32, m:lo32} via 64-bit CAS.
__device__ inline void lse_merge(unsigned long long* addr, float m, float s) {
  unsigned long long old = *(volatile unsigned long long*)addr;
  while (true) {
    float mo = __uint_as_float((unsigned)(old & 0xffffffffull));
    float so = __uint_as_float((unsigned)(old >> 32));
    float M = fmaxf(mo, m);
    float S = so * __expf(mo - M) + s * __expf(m - M);
    unsigned long long nv =
        ((unsigned long long)__float_as_uint(S) << 32) | (unsigned long long)__float_as_uint(M);
    unsigned long long prev = atomicCAS(addr, old, nv);
    if (prev == old) return;
    old = prev;
  }
}

__global__ void init_lse(unsigned long long* p, int n, int* cnt) {
  int i = blockIdx.x * blockDim.x + threadIdx.x;
  if (i < n)
    p[i] = (unsigned long long)__float_as_uint(-INFINITY);
  if (i < 2) cnt[i] = 0;
}

__global__ void build_rows(const int* __restrict__ tgt, int* __restrict__ cnt,
                           int* __restrict__ rows1, int* __restrict__ rows2, int N) {
  int n = blockIdx.x * blockDim.x + threadIdx.x;
  if (n >= N) return;
  const int t = tgt[n];
  if (t >= CUT1 && t < CUT2)      rows1[atomicAdd(&cnt[0], 1)] = n;
  else if (t >= CUT2)             rows2[atomicAdd(&cnt[1], 1)] = n;
}

// fp32 [R x K] (ldsrc) -> bf16 hi (and optional lo) [Rpad x Kpad], zero-padded.
__global__ void cvt_split(const float* __restrict__ src, int R, int K, int ldsrc,
                          u16* __restrict__ h, u16* __restrict__ l, int Kpad, int total) {
  const int idx = blockIdx.x * 256 + threadIdx.x;
  if (idx >= total) return;
  const int qpr = Kpad >> 2;
  const int r = idx / qpr;
  const int c0 = (idx - r * qpr) * 4;
  const bool inr = (r < R);
  ushort4 H, L;
  u16* hp = &H.x; u16* lp = &L.x;
#pragma unroll
  for (int j = 0; j < 4; ++j) {
    const int c = c0 + j;
    float v = (inr && c < K) ? src[(size_t)r * ldsrc + c] : 0.f;
    __hip_bfloat16 hb = __float2bfloat16(v);
    hp[j] = __builtin_bit_cast(u16, hb);
    if (l) {
      float hf = __bfloat162float(hb);
      lp[j] = __builtin_bit_cast(u16, __float2bfloat16(v - hf));
    }
  }
  *reinterpret_cast<ushort4*>(h + (size_t)r * Kpad + c0) = H;
  if (l) *reinterpret_cast<ushort4*>(l + (size_t)r * Kpad + c0) = L;
}

// ---------------------------------------------------------------------------
// bf16 MFMA GEMM. 128x128 tile, 4 waves (2x2), wave = 4x4 frags of 16x16x32.
// NP=1: pure bf16 (hi only). NP=3: split hi/lo, hh+hl+lh products.
// SHARD=0 (ROWSHARD): XCD owns rows  -> A panels L2-resident, B streams.
// SHARD=1 (COLSHARD): XCD owns cols  -> B shard + small A resident (tails).
// MODE 0: store fp32 C.  MODE 1: per-row online LSE into lse[orig_row].
// ---------------------------------------------------------------------------
template<int MODE, int NP, int SHARD>
__global__ __launch_bounds__(256, (NP == 1 ? 4 : 3))
void gemm_mfma(const u16* __restrict__ Ah, const u16* __restrict__ Al, int lda,
               const u16* __restrict__ Bh, const u16* __restrict__ Bl, int ldb,
               const float* __restrict__ bias1, const float* __restrict__ bias2, int v_split,
               int Nrows, int V, int nk, int rb, int cb, int sdiv,
               float* __restrict__ C, int ldc,
               unsigned long long* __restrict__ lse,
               const int* __restrict__ rowidx, const int* __restrict__ rowcnt)
{
  // HW round-robins blockIdx.x across XCDs: xcd = blockIdx.x & 7.
  const int xcd = blockIdx.x & 7, sub = blockIdx.x >> 3;
  int rt, ct;
  if (SHARD == 0) { rt = xcd * sdiv + (sub % sdiv); ct = sub / sdiv; }
  else            { rt = sub % rb;                  ct = xcd * sdiv + sub / rb; }
  if (rt >= rb || ct >= cb) return;

  const int nrows = rowcnt ? *rowcnt : Nrows;
  const int r0 = rt * 128;
  if (r0 >= nrows) return;
  const int c0 = ct * 128;

  __shared__ alignas(16) u16 lds[(NP == 1 ? 2 : 4) * 4096];  // tiles [128][32]
  u16* AhS = lds;
  u16* AlS = lds + 4096;                       // NP==3 only
  u16* BhS = lds + (NP == 3 ? 8192 : 4096);
  u16* BlS = lds + 12288;                      // NP==3 only

  const int tid = threadIdx.x;
  const int w = tid >> 6, l = tid & 63;
  const int wr = w >> 1, wc = w & 1;

  // staging: wave w owns tile rows [w*32, w*32+32) as two 16-row groups;
  // lane covers row (l>>2), 16B slot (l&3); LDS dest = base + lane*16.
  const int sl = l & 3, rw = l >> 2;
  int ar0 = r0 + w * 32 + rw;      if (ar0 > nrows - 1) ar0 = nrows - 1;
  int ar1 = r0 + w * 32 + 16 + rw; if (ar1 > nrows - 1) ar1 = nrows - 1;
  if (rowidx) { ar0 = rowidx[ar0]; ar1 = rowidx[ar1]; }
  const int br0 = c0 + w * 32 + rw, br1 = br0 + 16;

  const u16* gAh0 = Ah + (size_t)ar0 * lda + sl * 8;
  const u16* gAh1 = Ah + (size_t)ar1 * lda + sl * 8;
  const u16* gBh0 = Bh + (size_t)br0 * ldb + sl * 8;
  const u16* gBh1 = Bh + (size_t)br1 * ldb + sl * 8;
  const u16* gAl0 = (NP == 3) ? Al + (size_t)ar0 * lda + sl * 8 : nullptr;
  const u16* gAl1 = (NP == 3) ? Al + (size_t)ar1 * lda + sl * 8 : nullptr;
  const u16* gBl0 = (NP == 3) ? Bl + (size_t)br0 * ldb + sl * 8 : nullptr;
  const u16* gBl1 = (NP == 3) ? Bl + (size_t)br1 * ldb + sl * 8 : nullptr;

  u16* dAh0 = AhS + w * 1024;  u16* dAh1 = dAh0 + 512;   // wave-uniform bases
  u16* dBh0 = BhS + w * 1024;  u16* dBh1 = dBh0 + 512;
  u16* dAl0 = AlS + w * 1024;  u16* dAl1 = dAl0 + 512;
  u16* dBl0 = BlS + w * 1024;  u16* dBl1 = dBl0 + 512;

  f32x4 acc[4][4] = {};

  for (int kt = 0; kt < nk; ++kt) {
    const int k0 = kt * 32;
    gload16(gAh0 + k0, dAh0);  gload16(gAh1 + k0, dAh1);
    gload16(gBh0 + k0, dBh0);  gload16(gBh1 + k0, dBh1);
    if constexpr (NP == 3) {
      gload16(gAl0 + k0, dAl0);  gload16(gAl1 + k0, dAl1);
      gload16(gBl0 + k0, dBl0);  gload16(gBl1 + k0, dBl1);
    }
    __syncthreads();   // drains vmcnt(0): DMA complete

    short8 fah[4], fbh[4], fal[4], fbl[4];
    const int rr = l & 15;
    const int kq = (l >> 4) * 8;
#pragma unroll
    for (int m = 0; m < 4; ++m) {
      const int row = wr * 64 + m * 16 + rr;
      fah[m] = *(const short8*)(AhS + row * 32 + kq);
      if constexpr (NP == 3) fal[m] = *(const short8*)(AlS + row * 32 + kq);
    }
#pragma unroll
    for (int n = 0; n < 4; ++n) {
      const int col = wc * 64 + n * 16 + rr;
      fbh[n] = *(const short8*)(BhS + col * 32 + kq);
      if constexpr (NP == 3) fbl[n] = *(const short8*)(BlS + col * 32 + kq);
    }
#pragma unroll
    for (int m = 0; m < 4; ++m)
#pragma unroll
      for (int n = 0; n < 4; ++n) {
        acc[m][n] = __builtin_amdgcn_mfma_f32_16x16x32_bf16(fah[m], fbh[n], acc[m][n], 0, 0, 0);
        if constexpr (NP == 3) {
          acc[m][n] = __builtin_amdgcn_mfma_f32_16x16x32_bf16(fah[m], fbl[n], acc[m][n], 0, 0, 0);
          acc[m][n] = __builtin_amdgcn_mfma_f32_16x16x32_bf16(fal[m], fbh[n], acc[m][n], 0, 0, 0);
        }
      }
    __syncthreads();   // protect LDS from next iteration's DMA
  }

  // C/D layout (m89-verified): col = lane&15, row = (lane>>4)*4 + reg
  if (MODE == 0) {
#pragma unroll
    for (int m = 0; m < 4; ++m)
#pragma unroll
      for (int r = 0; r < 4; ++r) {
        const int row = r0 + wr * 64 + m * 16 + (l >> 4) * 4 + r;
        if (row < Nrows) {
#pragma unroll
          for (int n = 0; n < 4; ++n)
            C[(size_t)row * ldc + c0 + wc * 64 + n * 16 + (l & 15)] = acc[m][n][r];
        }
      }
  } else {
    float biasv[4];
#pragma unroll
    for (int n = 0; n < 4; ++n) {
      const int cc = c0 + wc * 64 + n * 16 + (l & 15);
      biasv[n] = (cc < V) ? ((cc < v_split) ? bias1[cc] : bias2[cc - v_split]) : -INFINITY;
    }
#pragma unroll
    for (int m = 0; m < 4; ++m)
#pragma unroll
      for (int r = 0; r < 4; ++r) {
        float v0 = acc[m][0][r] + biasv[0], v1 = acc[m][1][r] + biasv[1];
        float v2 = acc[m][2][r] + biasv[2], v3 = acc[m][3][r] + biasv[3];
        float mx = fmaxf(fmaxf(v0, v1), fmaxf(v2, v3));
#pragma unroll
        for (int d = 1; d < 16; d <<= 1) mx = fmaxf(mx, __shfl_xor(mx, d));
        float s = __expf(v0 - mx) + __expf(v1 - mx) + __expf(v2 - mx) + __expf(v3 - mx);
#pragma unroll
        for (int d = 1; d < 16; d <<= 1) s += __shfl_xor(s, d);
        const int row = r0 + wr * 64 + m * 16 + (l >> 4) * 4 + r;
        if ((l & 15) == 0 && row < nrows && mx != -INFINITY) {
          const int orig = rowidx ? rowidx[row] : row;
          lse_merge(&lse[orig], mx, s);
        }
      }
  }
}

// ---------------------------------------------------------------------------
// fp32 fallback GEMM (vector FMA), used when ws is too small for bf16 buffers.
// ---------------------------------------------------------------------------
constexpr int TM = 128, TN = 128, TK = 16;
constexpr int LDS_PAD = 4;

template<int MODE>
__global__ __launch_bounds__(256, 2)
void gemm_kernel(const float* __restrict__ A, int lda,
                 const float* __restrict__ B1, const float* __restrict__ B2, int v_split,
                 const float* __restrict__ bias1, const float* __restrict__ bias2,
                 int N, int V, int K,
                 float* __restrict__ C, int ldc,
                 unsigned long long* __restrict__ lse,
                 const int* __restrict__ rowidx, const int* __restrict__ rowcnt)
{
  const int nrows = rowcnt ? *rowcnt : N;
  const int r0 = blockIdx.x * TM;
  if (r0 >= nrows) return;
  const int c0 = blockIdx.y * TN;

  __shared__ float As[TK][TM + LDS_PAD];
  __shared__ float Bs[TK][TN + LDS_PAD];
  const int tid = threadIdx.x;
  const int tx = tid & 15, ty = tid >> 4;

  float acc[8][8];
#pragma unroll
  for (int i = 0; i < 8; ++i)
#pragma unroll
    for (int j = 0; j < 8; ++j) acc[i][j] = 0.f;

  const int ktiles = (K + TK - 1) / TK;
  const bool kvec = ((K & 3) == 0);

  for (int kt = 0; kt < ktiles; ++kt) {
    const int k0 = kt * TK;
#pragma unroll
    for (int i = 0; i < 2; ++i) {
      const int idx = tid + i * 256;
      const int rr  = idx >> 2;
      const int kq  = (idx & 3) << 2;
      int gr = r0 + rr; if (gr >= nrows) gr = nrows - 1;
      if (rowidx) gr = rowidx[gr];
      const float4 av = *reinterpret_cast<const float4*>(A + (size_t)gr * lda + (k0 + kq));
      As[kq + 0][rr] = av.x; As[kq + 1][rr] = av.y;
      As[kq + 2][rr] = av.z; As[kq + 3][rr] = av.w;
      const int gc = c0 + rr;
      float4 bv = make_float4(0.f, 0.f, 0.f, 0.f);
      if (gc < V) {
        const float* Bp = (gc < v_split) ? (B1 + (size_t)gc * K)
                                         : (B2 + (size_t)(gc - v_split) * K);
        const int kk = k0 + kq;
        if (kvec && kk + 3 < K) {
          bv = *reinterpret_cast<const float4*>(Bp + kk);
        } else {
          bv.x = (kk + 0 < K) ? Bp[kk + 0] : 0.f;
          bv.y = (kk + 1 < K) ? Bp[kk + 1] : 0.f;
          bv.z = (kk + 2 < K) ? Bp[kk + 2] : 0.f;
          bv.w = (kk + 3 < K) ? Bp[kk + 3] : 0.f;
        }
      }
      Bs[kq + 0][rr] = bv.x; Bs[kq + 1][rr] = bv.y;
      Bs[kq + 2][rr] = bv.z; Bs[kq + 3][rr] = bv.w;
    }
    __syncthreads();
#pragma unroll
    for (int k = 0; k < TK; ++k) {
      float a[8], b[8];
      *reinterpret_cast<float4*>(&a[0]) = *reinterpret_cast<const float4*>(&As[k][4 * ty]);
      *reinterpret_cast<float4*>(&a[4]) = *reinterpret_cast<const float4*>(&As[k][64 + 4 * ty]);
      *reinterpret_cast<float4*>(&b[0]) = *reinterpret_cast<const float4*>(&Bs[k][4 * tx]);
      *reinterpret_cast<float4*>(&b[4]) = *reinterpret_cast<const float4*>(&Bs[k][64 + 4 * tx]);
#pragma unroll
      for (int i = 0; i < 8; ++i)
#pragma unroll
        for (int j = 0; j < 8; ++j)
          acc[i][j] = fmaf(a[i], b[j], acc[i][j]);
    }
    __syncthreads();
  }

  if (MODE == 0) {
#pragma unroll
    for (int i = 0; i < 8; ++i) {
      const int ri = r0 + 4 * ty + (i & 3) + (i >> 2) * 64;
      if (ri >= N) continue;
#pragma unroll
      for (int jh = 0; jh < 2; ++jh) {
        float4 v;
        float* vp = reinterpret_cast<float*>(&v);
#pragma unroll
        for (int j = 0; j < 4; ++j) {
          const int cj = c0 + 4 * tx + j + jh * 64;
          vp[j] = (cj < V) ? acc[i][j + jh * 4] : 0.f;
        }
        *reinterpret_cast<float4*>(C + (size_t)ri * ldc + (c0 + 4 * tx + jh * 64)) = v;
      }
    }
  } else {
    float bv[8];
#pragma unroll
    for (int jj = 0; jj < 8; ++jj) {
      const int cj = c0 + 4 * tx + (jj & 3) + (jj >> 2) * 64;
      bv[jj] = (cj < V) ? ((cj < v_split) ? bias1[cj] : bias2[cj - v_split]) : 0.f;
    }
#pragma unroll
    for (int i = 0; i < 8; ++i)
#pragma unroll
      for (int jj = 0; jj < 8; ++jj) {
        const int cj = c0 + 4 * tx + (jj & 3) + (jj >> 2) * 64;
        acc[i][jj] = (cj < V) ? (acc[i][jj] + bv[jj]) : -INFINITY;
      }
#pragma unroll
    for (int i = 0; i < 8; ++i) {
      float m = acc[i][0];
#pragma unroll
      for (int jj = 1; jj < 8; ++jj) m = fmaxf(m, acc[i][jj]);
#pragma unroll
      for (int d = 1; d < 16; d <<= 1) m = fmaxf(m, __shfl_xor(m, d));
      float s = 0.f;
#pragma unroll
      for (int jj = 0; jj < 8; ++jj) s += __expf(acc[i][jj] - m);
#pragma unroll
      for (int d = 1; d < 16; d <<= 1) s += __shfl_xor(s, d);
      const int ri = r0 + 4 * ty + (i & 3) + (i >> 2) * 64;
      if (tx == 0 && ri < nrows) {
        const int orig = rowidx ? rowidx[ri] : ri;
        lse_merge(&lse[orig], m, s);
      }
    }
  }
}

// One wave per token: gathered dot products for the picked logits.
__global__ __launch_bounds__(256)
void pick_kernel(const float* __restrict__ x, const int* __restrict__ tgt,
                 const float* __restrict__ tw0, const float* __restrict__ tb0,
                 const float* __restrict__ cw,  const float* __restrict__ cb,
                 const float* __restrict__ tw1, const float* __restrict__ tb1,
                 const float* __restrict__ tw2, const float* __restrict__ tb2,
                 const float* __restrict__ xt1, const float* __restrict__ xt2,
                 float* __restrict__ pick0, float* __restrict__ pickc,
                 float* __restrict__ pickt, int N)
{
  const int wid  = (blockIdx.x * blockDim.x + threadIdx.x) >> 6;
  const int lane = threadIdx.x & 63;
  if (wid >= N) return;
  const int t = tgt[wid];
  if (t >= 1 && t < CUT1) {
    const float4* xp = reinterpret_cast<const float4*>(x + (size_t)wid * DIM);
    const float4* wp = reinterpret_cast<const float4*>(tw0 + (size_t)t * DIM);
    float s = 0.f;
#pragma unroll
    for (int it = 0; it < DIM / 256; ++it) {
      float4 a = xp[lane + it * 64];
      float4 b = wp[lane + it * 64];
      s += a.x * b.x + a.y * b.y + a.z * b.z + a.w * b.w;
    }
#pragma unroll
    for (int d = 1; d < 64; d <<= 1) s += __shfl_xor(s, d);
    if (lane == 0) pick0[wid] = s + tb0[t];
  } else if (t >= CUT1) {
    const int i2 = (t < CUT2) ? 0 : 1;
    const float4* xp = reinterpret_cast<const float4*>(x + (size_t)wid * DIM);
    const float4* wp = reinterpret_cast<const float4*>(cw + (size_t)i2 * DIM);
    float s = 0.f;
#pragma unroll
    for (int it = 0; it < DIM / 256; ++it) {
      float4 a = xp[lane + it * 64];
      float4 b = wp[lane + it * 64];
      s += a.x * b.x + a.y * b.y + a.z * b.z + a.w * b.w;
    }
#pragma unroll
    for (int d = 1; d < 64; d <<= 1) s += __shfl_xor(s, d);
    const int K  = i2 ? P2 : P1;
    const int ld = i2 ? XT2_LD : XT1_LD;
    const int tj = t - (i2 ? CUT2 : CUT1);
    const float* xr = (i2 ? xt2 : xt1) + (size_t)wid * ld;
    const float* wr = (i2 ? tw2 : tw1) + (size_t)tj * K;
    float s2 = 0.f;
    for (int k = lane; k < K; k += 64) s2 += xr[k] * wr[k];
#pragma unroll
    for (int d = 1; d < 64; d <<= 1) s2 += __shfl_xor(s2, d);
    if (lane == 0) {
      pickc[wid] = s + cb[i2];
      pickt[wid] = s2 + (i2 ? tb2 : tb1)[tj];
    }
  }
}

__global__ void final_kernel(const int* __restrict__ tgt,
                             const unsigned long long* __restrict__ lse,
                             const float* __restrict__ pick0, const float* __restrict__ pickc,
                             const float* __restrict__ pickt,
                             float* __restrict__ out, int N)
{
  const int n = blockIdx.x * blockDim.x + threadIdx.x;
  if (n >= N) return;
  const int t = tgt[n];
  float y = 0.f;
  if (t >= 1 && t < CUT1) {
    unsigned long long p = lse[n];
    float l0 = __uint_as_float((unsigned)(p & 0xffffffffull)) +
               logf(__uint_as_float((unsigned)(p >> 32)));
    y = -(pick0[n] - l0);
  } else if (t >= CUT1) {
    const int i2 = (t < CUT2) ? 0 : 1;
    unsigned long long p = lse[n];
    float l0 = __uint_as_float((unsigned)(p & 0xffffffffull)) +
               logf(__uint_as_float((unsigned)(p >> 32)));
    unsigned long long q = lse[(size_t)(i2 + 1) * N + n];
    float li = __uint_as_float((unsigned)(q & 0xffffffffull)) +
               logf(__uint_as_float((unsigned)(q >> 32)));
    y = -((pickc[n] - l0) + (pickt[n] - li));
  }
  out[n] = y;
}

extern "C" void kernel_launch(void* const* d_in, const int* in_sizes, int n_in,
                              void* d_out, int out_size, void* d_ws, size_t ws_size,
                              hipStream_t stream)
{
  const float* x   = (const float*)d_in[0];
  const int*   tgt = (const int*)d_in[1];
  const float* tw0 = (const float*)d_in[2];
  const float* tb0 = (const float*)d_in[3];
  const float* cw  = (const float*)d_in[4];
  const float* cb  = (const float*)d_in[5];
  const float* tw1 = (const float*)d_in[6];
  const float* tb1 = (const float*)d_in[7];
  const float* aw1 = (const float*)d_in[8];
  const float* tw2 = (const float*)d_in[9];
  const float* tb2 = (const float*)d_in[10];
  const float* aw2 = (const float*)d_in[11];
  float* out = (float*)d_out;
  const int N = in_sizes[1];  // B*S tokens

  // ---- workspace layout ----
  size_t off = 0;
  auto alloc = [&](size_t bytes) { size_t o = off; off += (bytes + 255) & ~(size_t)255; return o; };
  char* ws = (char*)d_ws;
  const size_t o_lse   = alloc((size_t)3 * N * 8);
  const size_t o_pick0 = alloc((size_t)N * 4);
  const size_t o_pickc = alloc((size_t)N * 4);
  const size_t o_pickt = alloc((size_t)N * 4);
  const size_t o_cnt   = alloc(2 * 4);
  const size_t o_rows1 = alloc((size_t)N * 4);
  const size_t o_rows2 = alloc((size_t)N * 4);
  const size_t o_xt1   = alloc((size_t)N * XT1_LD * 4);
  const size_t o_xt2   = alloc((size_t)N * XT2_LD * 4);
  // MFMA-path bf16 buffers (hi everywhere; lo only for x and adapt weights)
  const size_t o_xh   = alloc((size_t)N * DIM * 2);
  const size_t o_xl   = alloc((size_t)N * DIM * 2);
  const size_t o_whh  = alloc((size_t)VPAD0 * DIM * 2);
  const size_t o_t1h  = alloc((size_t)VPAD1 * K1P * 2);
  const size_t o_t2h  = alloc((size_t)VPAD2 * K2P * 2);
  const size_t o_a1h  = alloc((size_t)A1R * DIM * 2);
  const size_t o_a1l  = alloc((size_t)A1R * DIM * 2);
  const size_t o_a2h  = alloc((size_t)A2R * DIM * 2);
  const size_t o_a2l  = alloc((size_t)A2R * DIM * 2);
  const size_t o_x1h  = alloc((size_t)N * K1P * 2);
  const size_t o_x2h  = alloc((size_t)N * K2P * 2);
  const size_t need_mfma = off;

  unsigned long long* lse = (unsigned long long*)(ws + o_lse);
  float* pick0 = (float*)(ws + o_pick0);
  float* pickc = (float*)(ws + o_pickc);
  float* pickt = (float*)(ws + o_pickt);
  int*   cnt   = (int*)(ws + o_cnt);
  int*   rows1 = (int*)(ws + o_rows1);
  int*   rows2 = (int*)(ws + o_rows2);
  float* xt1   = (float*)(ws + o_xt1);
  float* xt2   = (float*)(ws + o_xt2);

  init_lse<<<dim3((3 * N + 255) / 256), dim3(256), 0, stream>>>(lse, 3 * N, cnt);
  build_rows<<<dim3((N + 255) / 256), dim3(256), 0, stream>>>(tgt, cnt, rows1, rows2, N);

  const int rb = (N + 127) / 128;          // 32 row tiles
  const int rpx = (rb + 7) / 8;            // rows per XCD (ROWSHARD)

  if (ws_size >= need_mfma) {
    // ---------------- bf16 MFMA path ----------------
    u16* xh  = (u16*)(ws + o_xh),  *xl  = (u16*)(ws + o_xl);
    u16* whh = (u16*)(ws + o_whh);
    u16* t1h = (u16*)(ws + o_t1h);
    u16* t2h = (u16*)(ws + o_t2h);
    u16* a1h = (u16*)(ws + o_a1h), *a1l = (u16*)(ws + o_a1l);
    u16* a2h = (u16*)(ws + o_a2h), *a2l = (u16*)(ws + o_a2l);
    u16* x1h = (u16*)(ws + o_x1h);
    u16* x2h = (u16*)(ws + o_x2h);

    auto cvt = [&](const float* src, int R, int K, int ldsrc, u16* h, u16* l,
                   int Kpad, int Rpad) {
      const int total = Rpad * (Kpad >> 2);
      cvt_split<<<dim3((total + 255) / 256), 256, 0, stream>>>(src, R, K, ldsrc, h, l, Kpad, total);
    };
    cvt(x,   N,    DIM, DIM, xh, xl, DIM, N);
    cvt(tw0, CUT1, DIM, DIM, whh, nullptr, DIM, CUT1);
    cvt(cw,  2,    DIM, DIM, whh + (size_t)CUT1 * DIM, nullptr, DIM, 96);
    cvt(tw1, CUT2 - CUT1, P1, P1, t1h, nullptr, K1P, VPAD1);
    cvt(tw2, NTOK - CUT2, P2, P2, t2h, nullptr, K2P, VPAD2);
    cvt(aw1, P1, DIM, DIM, a1h, a1l, DIM, A1R);
    cvt(aw2, P2, DIM, DIM, a2h, a2l, DIM, A2R);

    // adapt projections: bf16x3, ROWSHARD
    gemm_mfma<0, 3, 0><<<dim3(8 * rpx * (A1R / 128)), 256, 0, stream>>>(
        xh, xl, DIM, a1h, a1l, DIM, nullptr, nullptr, 0,
        N, A1R, DIM / 32, rb, A1R / 128, rpx, xt1, XT1_LD, nullptr, nullptr, nullptr);
    gemm_mfma<0, 3, 0><<<dim3(8 * rpx * (A2R / 128)), 256, 0, stream>>>(
        xh, xl, DIM, a2h, a2l, DIM, nullptr, nullptr, 0,
        N, A2R, DIM / 32, rb, A2R / 128, rpx, xt2, XT2_LD, nullptr, nullptr, nullptr);
    cvt(xt1, N, K1P, XT1_LD, x1h, nullptr, K1P, N);
    cvt(xt2, N, K2P, XT2_LD, x2h, nullptr, K2P, N);

    // head LSE: pure bf16, ROWSHARD (A panels resident per XCD)
    gemm_mfma<1, 1, 0><<<dim3(8 * rpx * (VPAD0 / 128)), 256, 0, stream>>>(
        xh, nullptr, DIM, whh, nullptr, DIM, tb0, cb, CUT1,
        N, CUT1 + 2, DIM / 32, rb, VPAD0 / 128, rpx, nullptr, 0, lse, nullptr, nullptr);
    // tail1 LSE: pure bf16, COLSHARD (B shard resident per XCD), compacted rows
    {
      const int cb1 = VPAD1 / 128, cpx = (cb1 + 7) / 8;
      gemm_mfma<1, 1, 1><<<dim3(8 * cpx * rb), 256, 0, stream>>>(
          x1h, nullptr, K1P, t1h, nullptr, K1P, tb1, tb1, CUT2 - CUT1,
          N, CUT2 - CUT1, K1P / 32, rb, cb1, cpx, nullptr, 0, lse + N, rows1, cnt + 0);
    }
    // tail2 LSE
    {
      const int cb2 = VPAD2 / 128, cpx = (cb2 + 7) / 8;
      gemm_mfma<1, 1, 1><<<dim3(8 * cpx * rb), 256, 0, stream>>>(
          x2h, nullptr, K2P, t2h, nullptr, K2P, tb2, tb2, NTOK - CUT2,
          N, NTOK - CUT2, K2P / 32, rb, cb2, cpx, nullptr, 0, lse + 2 * N, rows2, cnt + 1);
    }
  } else {
    // ---------------- fp32 fallback path ----------------
    gemm_kernel<0><<<dim3(rb, (P1 + TN - 1) / TN), 256, 0, stream>>>(
        x, DIM, aw1, aw1, P1, nullptr, nullptr, N, P1, DIM, xt1, XT1_LD, nullptr,
        nullptr, nullptr);
    gemm_kernel<0><<<dim3(rb, (P2 + TN - 1) / TN), 256, 0, stream>>>(
        x, DIM, aw2, aw2, P2, nullptr, nullptr, N, P2, DIM, xt2, XT2_LD, nullptr,
        nullptr, nullptr);
    gemm_kernel<1><<<dim3(rb, (CUT1 + 2 + TN - 1) / TN), 256, 0, stream>>>(
        x, DIM, tw0, cw, CUT1, tb0, cb, N, CUT1 + 2, DIM, nullptr, 0, lse,
        nullptr, nullptr);
    gemm_kernel<1><<<dim3(rb, (CUT2 - CUT1 + TN - 1) / TN), 256, 0, stream>>>(
        xt1, XT1_LD, tw1, tw1, CUT2 - CUT1, tb1, tb1, N, CUT2 - CUT1, P1, nullptr, 0, lse + N,
        rows1, cnt + 0);
    gemm_kernel<1><<<dim3(rb, (NTOK - CUT2 + TN - 1) / TN), 256, 0, stream>>>(
        xt2, XT2_LD, tw2, tw2, NTOK - CUT2, tb2, tb2, N, NTOK - CUT2, P2, nullptr, 0, lse + 2 * N,
        rows2, cnt + 1);
  }

  pick_kernel<<<dim3((N + 3) / 4), 256, 0, stream>>>(
      x, tgt, tw0, tb0, cw, cb, tw1, tb1, tw2, tb2, xt1, xt2, pick0, pickc, pickt, N);
  final_kernel<<<dim3((N + 255) / 256), 256, 0, stream>>>(
      tgt, lse, pick0, pickc, pickt, out, N);
}

// Round 12
// 589.668 us; speedup vs baseline: 3.4950x; 3.4950x over previous
//
#include <hip/hip_runtime.h>
#include <hip/hip_bf16.h>
#include <math.h>

// ---------------------------------------------------------------------------
// Adaptive-softmax NLL, MI355X.
// r10-r12: LSE partial slots indexed by (column-tile, wave-column-half):
// part[(ct*2+wc)*N + row] -- single writer per slot (fixes r9's overwrite
// race that dropped half of each tile's mass). Pipeline: double-buffered
// LDS + counted vmcnt; race-free partials + reduce pass; LSE GEMMs pure
// bf16; adapt projections bf16x3. ROWSHARD for head/adapt, COLSHARD tails.
// Fallback (small ws): fp32 vector-FMA path with CAS.
// ---------------------------------------------------------------------------

#define CUT1 20000
#define CUT2 40000
#define NTOK 50257
#define DIM  1024
#define P1   341
#define P2   113
#define XT1_LD 384
#define XT2_LD 128

#define VPAD0 20096   // head vocab 20002 -> 157 tiles of 128
#define VPAD1 20096   // tail1 vocab 20000
#define VPAD2 10368   // tail2 vocab 10257 -> 81 tiles
#define K1P   352
#define K2P   128
#define A1R   384
#define A2R   128

#define NCT0  157     // column tiles per section
#define NCT1  157
#define NCT2  81
// partial slots per section = 2 * NCT (two column-half waves per tile)
#define NSL0  (2 * NCT0)
#define NSL1  (2 * NCT1)
#define NSL2  (2 * NCT2)
#define NSLT  (NSL0 + NSL1 + NSL2)

typedef unsigned short u16;
typedef __attribute__((ext_vector_type(8))) short short8;
typedef __attribute__((ext_vector_type(4))) float f32x4;

typedef __attribute__((address_space(1))) const unsigned int gu32;
typedef __attribute__((address_space(3))) unsigned int su32;

__device__ __forceinline__ void gload16(const u16* g, u16* s) {
  __builtin_amdgcn_global_load_lds((gu32*)g, (su32*)s, 16, 0, 0);
}

__device__ inline unsigned long long pack_ms(float m, float s) {
  return ((unsigned long long)__float_as_uint(s) << 32) | (unsigned long long)__float_as_uint(m);
}

// CAS online merge -- fp32 fallback path only.
__device__ inline void lse_merge(unsigned long long* addr, float m, float s) {
  unsigned long long old = *(volatile unsigned long long*)addr;
  while (true) {
    float mo = __uint_as_float((unsigned)(old & 0xffffffffull));
    float so = __uint_as_float((unsigned)(old >> 32));
    float M = fmaxf(mo, m);
    float S = so * __expf(mo - M) + s * __expf(m - M);
    unsigned long long nv = pack_ms(M, S);
    unsigned long long prev = atomicCAS(addr, old, nv);
    if (prev == old) return;
    old = prev;
  }
}

// init lse (3N), partials (ptot), counters.
__global__ void init_ws(unsigned long long* lse, int nl, unsigned long long* part,
                        int ptot, int* cnt) {
  int i = blockIdx.x * blockDim.x + threadIdx.x;
  const unsigned long long iv = (unsigned long long)__float_as_uint(-INFINITY);
  if (i < nl) lse[i] = iv;
  if (i < ptot) part[i] = iv;
  if (i < 2) cnt[i] = 0;
}

__global__ void build_rows(const int* __restrict__ tgt, int* __restrict__ cnt,
                           int* __restrict__ rows1, int* __restrict__ rows2, int N) {
  int n = blockIdx.x * blockDim.x + threadIdx.x;
  if (n >= N) return;
  const int t = tgt[n];
  if (t >= CUT1 && t < CUT2)      rows1[atomicAdd(&cnt[0], 1)] = n;
  else if (t >= CUT2)             rows2[atomicAdd(&cnt[1], 1)] = n;
}

// fp32 [R x K] (ldsrc) -> bf16 hi (and optional lo) [Rpad x Kpad], zero-padded.
__global__ void cvt_split(const float* __restrict__ src, int R, int K, int ldsrc,
                          u16* __restrict__ h, u16* __restrict__ l, int Kpad, int total) {
  const int idx = blockIdx.x * 256 + threadIdx.x;
  if (idx >= total) return;
  const int qpr = Kpad >> 2;
  const int r = idx / qpr;
  const int c0 = (idx - r * qpr) * 4;
  const bool inr = (r < R);
  ushort4 H, L;
  u16* hp = &H.x; u16* lp = &L.x;
#pragma unroll
  for (int j = 0; j < 4; ++j) {
    const int c = c0 + j;
    float v = (inr && c < K) ? src[(size_t)r * ldsrc + c] : 0.f;
    __hip_bfloat16 hb = __float2bfloat16(v);
    hp[j] = __builtin_bit_cast(u16, hb);
    if (l) {
      float hf = __bfloat162float(hb);
      lp[j] = __builtin_bit_cast(u16, __float2bfloat16(v - hf));
    }
  }
  *reinterpret_cast<ushort4*>(h + (size_t)r * Kpad + c0) = H;
  if (l) *reinterpret_cast<ushort4*>(l + (size_t)r * Kpad + c0) = L;
}

// Merge partials over slots: one wave per row.
__global__ void reduce_lse(const unsigned long long* __restrict__ part, int nsl, int N,
                           unsigned long long* __restrict__ lse) {
  const int row  = (blockIdx.x * blockDim.x + threadIdx.x) >> 6;
  const int lane = threadIdx.x & 63;
  if (row >= N) return;
  float m = -INFINITY, s = 0.f;
  for (int c = lane; c < nsl; c += 64) {
    unsigned long long p = part[(size_t)c * N + row];
    float pm = __uint_as_float((unsigned)(p & 0xffffffffull));
    float ps = __uint_as_float((unsigned)(p >> 32));
    float M = fmaxf(m, pm);
    if (M != -INFINITY) {           // s==0 whenever m==-inf -> safe
      s = s * __expf(m - M) + ps * __expf(pm - M);
      m = M;
    }
  }
#pragma unroll
  for (int d = 1; d < 64; d <<= 1) {
    float om = __shfl_xor(m, d), os = __shfl_xor(s, d);
    float M = fmaxf(m, om);
    if (M != -INFINITY) {
      s = s * __expf(m - M) + os * __expf(om - M);
      m = M;
    }
  }
  if (lane == 0) lse[row] = pack_ms(m, s);
}

// ---------------------------------------------------------------------------
// bf16 MFMA GEMM. 128x128 tile, 4 waves (2x2), wave = 4x4 frags of 16x16x32.
// Double-buffered LDS; next tile's global_load_lds issued before waiting on
// the current tile (s_waitcnt vmcnt(NLOADS), never 0 mid-loop).
// NP=1 pure bf16; NP=3 split hi/lo (hh+hl+lh).
// SHARD=0: XCD owns rows (A resident). SHARD=1: XCD owns cols (tails).
// MODE 0: store fp32 C. MODE 1: per-(col-tile, wave-col-half) LSE partial:
//   part[(ct*2 + wc)*Nrows + orig] -- single writer per slot.
// ---------------------------------------------------------------------------
template<int MODE, int NP, int SHARD>
__global__ __launch_bounds__(256, (NP == 1 ? 4 : 2))
void gemm_mfma(const u16* __restrict__ Ah, const u16* __restrict__ Al, int lda,
               const u16* __restrict__ Bh, const u16* __restrict__ Bl, int ldb,
               const float* __restrict__ bias1, const float* __restrict__ bias2, int v_split,
               int Nrows, int V, int nk, int rb, int cb, int sdiv,
               float* __restrict__ C, int ldc,
               unsigned long long* __restrict__ part,
               const int* __restrict__ rowidx, const int* __restrict__ rowcnt)
{
  const int xcd = blockIdx.x & 7, sub = blockIdx.x >> 3;
  int rt, ct;
  if (SHARD == 0) { rt = xcd * sdiv + (sub % sdiv); ct = sub / sdiv; }
  else            { rt = sub % rb;                  ct = xcd * sdiv + sub / rb; }
  if (rt >= rb || ct >= cb) return;

  const int nrows = rowcnt ? *rowcnt : Nrows;
  const int r0 = rt * 128;
  if (r0 >= nrows) return;
  const int c0 = ct * 128;

  constexpr int BUFSZ = (NP == 1 ? 2 : 4) * 4096;   // u16 per buffer
  __shared__ alignas(16) u16 lds[2 * BUFSZ];

  const int tid = threadIdx.x;
  const int w = tid >> 6, l = tid & 63;
  const int wr = w >> 1, wc = w & 1;

  // staging: wave w owns tile rows [w*32, w*32+32) as two 16-row groups;
  // lane covers row (l>>2), 16B slot (l&3); LDS dest = base + lane*16.
  const int sl = l & 3, rw = l >> 2;
  int ar0 = r0 + w * 32 + rw;      if (ar0 > nrows - 1) ar0 = nrows - 1;
  int ar1 = r0 + w * 32 + 16 + rw; if (ar1 > nrows - 1) ar1 = nrows - 1;
  if (rowidx) { ar0 = rowidx[ar0]; ar1 = rowidx[ar1]; }
  const int br0 = c0 + w * 32 + rw, br1 = br0 + 16;

  const u16* gAh0 = Ah + (size_t)ar0 * lda + sl * 8;
  const u16* gAh1 = Ah + (size_t)ar1 * lda + sl * 8;
  const u16* gBh0 = Bh + (size_t)br0 * ldb + sl * 8;
  const u16* gBh1 = Bh + (size_t)br1 * ldb + sl * 8;
  const u16* gAl0 = (NP == 3) ? Al + (size_t)ar0 * lda + sl * 8 : nullptr;
  const u16* gAl1 = (NP == 3) ? Al + (size_t)ar1 * lda + sl * 8 : nullptr;
  const u16* gBl0 = (NP == 3) ? Bl + (size_t)br0 * ldb + sl * 8 : nullptr;
  const u16* gBl1 = (NP == 3) ? Bl + (size_t)br1 * ldb + sl * 8 : nullptr;

  auto STAGE = [&](int buf, int kt) {
    const int k0 = kt * 32;
    u16* base = lds + buf * BUFSZ;
    u16* dA0 = base + w * 1024;                           u16* dA1 = dA0 + 512;
    u16* dB0 = base + (NP == 3 ? 8192 : 4096) + w * 1024; u16* dB1 = dB0 + 512;
    gload16(gAh0 + k0, dA0);  gload16(gAh1 + k0, dA1);
    gload16(gBh0 + k0, dB0);  gload16(gBh1 + k0, dB1);
    if constexpr (NP == 3) {
      u16* dAl0 = base + 4096  + w * 1024;  u16* dAl1 = dAl0 + 512;
      u16* dBl0 = base + 12288 + w * 1024;  u16* dBl1 = dBl0 + 512;
      gload16(gAl0 + k0, dAl0);  gload16(gAl1 + k0, dAl1);
      gload16(gBl0 + k0, dBl0);  gload16(gBl1 + k0, dBl1);
    }
  };

  f32x4 acc[4][4] = {};
  const int rr = l & 15;
  const int kq = (l >> 4) * 8;

  STAGE(0, 0);
  for (int kt = 0; kt < nk; ++kt) {
    const int cur = kt & 1;
    if (kt + 1 < nk) {
      STAGE(cur ^ 1, kt + 1);
      // vmcnt retires in issue order: waiting to <=4 (<=8 for NP3) outstanding
      // guarantees buf[cur]'s loads have landed; barrier makes it all-waves.
      if constexpr (NP == 1) asm volatile("s_waitcnt vmcnt(4)" ::: "memory");
      else                   asm volatile("s_waitcnt vmcnt(8)" ::: "memory");
    } else {
      asm volatile("s_waitcnt vmcnt(0)" ::: "memory");
    }
    __builtin_amdgcn_sched_barrier(0);
    __builtin_amdgcn_s_barrier();
    __builtin_amdgcn_sched_barrier(0);   // pin ds_reads below the barrier

    const u16* base = lds + cur * BUFSZ;
    const u16* AhS = base;
    const u16* BhS = base + (NP == 3 ? 8192 : 4096);
    const u16* AlS = base + 4096;   // NP3 only
    const u16* BlS = base + 12288;  // NP3 only

    short8 fah[4], fbh[4], fal[4], fbl[4];
#pragma unroll
    for (int m = 0; m < 4; ++m) {
      const int row = wr * 64 + m * 16 + rr;
      fah[m] = *(const short8*)(AhS + row * 32 + kq);
      if constexpr (NP == 3) fal[m] = *(const short8*)(AlS + row * 32 + kq);
    }
#pragma unroll
    for (int n = 0; n < 4; ++n) {
      const int col = wc * 64 + n * 16 + rr;
      fbh[n] = *(const short8*)(BhS + col * 32 + kq);
      if constexpr (NP == 3) fbl[n] = *(const short8*)(BlS + col * 32 + kq);
    }
#pragma unroll
    for (int m = 0; m < 4; ++m)
#pragma unroll
      for (int n = 0; n < 4; ++n) {
        acc[m][n] = __builtin_amdgcn_mfma_f32_16x16x32_bf16(fah[m], fbh[n], acc[m][n], 0, 0, 0);
        if constexpr (NP == 3) {
          acc[m][n] = __builtin_amdgcn_mfma_f32_16x16x32_bf16(fah[m], fbl[n], acc[m][n], 0, 0, 0);
          acc[m][n] = __builtin_amdgcn_mfma_f32_16x16x32_bf16(fal[m], fbh[n], acc[m][n], 0, 0, 0);
        }
      }
    __builtin_amdgcn_s_barrier();   // all waves done reading buf[cur]
    __builtin_amdgcn_sched_barrier(0);
  }

  // C/D layout (m89-verified): col = lane&15, row = (lane>>4)*4 + reg
  if (MODE == 0) {
#pragma unroll
    for (int m = 0; m < 4; ++m)
#pragma unroll
      for (int r = 0; r < 4; ++r) {
        const int row = r0 + wr * 64 + m * 16 + (l >> 4) * 4 + r;
        if (row < Nrows) {
#pragma unroll
          for (int n = 0; n < 4; ++n)
            C[(size_t)row * ldc + c0 + wc * 64 + n * 16 + (l & 15)] = acc[m][n][r];
        }
      }
  } else {
    float biasv[4];
#pragma unroll
    for (int n = 0; n < 4; ++n) {
      const int cc = c0 + wc * 64 + n * 16 + (l & 15);
      biasv[n] = (cc < V) ? ((cc < v_split) ? bias1[cc] : bias2[cc - v_split]) : -INFINITY;
    }
    // slot for this block's (column tile, wave column half)
    unsigned long long* slot = part + (size_t)(ct * 2 + wc) * Nrows;
#pragma unroll
    for (int m = 0; m < 4; ++m)
#pragma unroll
      for (int r = 0; r < 4; ++r) {
        float v0 = acc[m][0][r] + biasv[0], v1 = acc[m][1][r] + biasv[1];
        float v2 = acc[m][2][r] + biasv[2], v3 = acc[m][3][r] + biasv[3];
        float mx = fmaxf(fmaxf(v0, v1), fmaxf(v2, v3));
#pragma unroll
        for (int d = 1; d < 16; d <<= 1) mx = fmaxf(mx, __shfl_xor(mx, d));
        float s = __expf(v0 - mx) + __expf(v1 - mx) + __expf(v2 - mx) + __expf(v3 - mx);
#pragma unroll
        for (int d = 1; d < 16; d <<= 1) s += __shfl_xor(s, d);
        const int row = r0 + wr * 64 + m * 16 + (l >> 4) * 4 + r;
        if ((l & 15) == 0 && row < nrows && mx != -INFINITY) {
          const int orig = rowidx ? rowidx[row] : row;
          slot[orig] = pack_ms(mx, s);   // single writer per slot
        }
      }
  }
}

// ---------------------------------------------------------------------------
// fp32 fallback GEMM (vector FMA) -- CAS merge path.
// ---------------------------------------------------------------------------
constexpr int TM = 128, TN = 128, TK = 16;
constexpr int LDS_PAD = 4;

template<int MODE>
__global__ __launch_bounds__(256, 2)
void gemm_kernel(const float* __restrict__ A, int lda,
                 const float* __restrict__ B1, const float* __restrict__ B2, int v_split,
                 const float* __restrict__ bias1, const float* __restrict__ bias2,
                 int N, int V, int K,
                 float* __restrict__ C, int ldc,
                 unsigned long long* __restrict__ lse,
                 const int* __restrict__ rowidx, const int* __restrict__ rowcnt)
{
  const int nrows = rowcnt ? *rowcnt : N;
  const int r0 = blockIdx.x * TM;
  if (r0 >= nrows) return;
  const int c0 = blockIdx.y * TN;

  __shared__ float As[TK][TM + LDS_PAD];
  __shared__ float Bs[TK][TN + LDS_PAD];
  const int tid = threadIdx.x;
  const int tx = tid & 15, ty = tid >> 4;

  float acc[8][8];
#pragma unroll
  for (int i = 0; i < 8; ++i)
#pragma unroll
    for (int j = 0; j < 8; ++j) acc[i][j] = 0.f;

  const int ktiles = (K + TK - 1) / TK;
  const bool kvec = ((K & 3) == 0);

  for (int kt = 0; kt < ktiles; ++kt) {
    const int k0 = kt * TK;
#pragma unroll
    for (int i = 0; i < 2; ++i) {
      const int idx = tid + i * 256;
      const int rr  = idx >> 2;
      const int kq  = (idx & 3) << 2;
      int gr = r0 + rr; if (gr >= nrows) gr = nrows - 1;
      if (rowidx) gr = rowidx[gr];
      const float4 av = *reinterpret_cast<const float4*>(A + (size_t)gr * lda + (k0 + kq));
      As[kq + 0][rr] = av.x; As[kq + 1][rr] = av.y;
      As[kq + 2][rr] = av.z; As[kq + 3][rr] = av.w;
      const int gc = c0 + rr;
      float4 bv = make_float4(0.f, 0.f, 0.f, 0.f);
      if (gc < V) {
        const float* Bp = (gc < v_split) ? (B1 + (size_t)gc * K)
                                         : (B2 + (size_t)(gc - v_split) * K);
        const int kk = k0 + kq;
        if (kvec && kk + 3 < K) {
          bv = *reinterpret_cast<const float4*>(Bp + kk);
        } else {
          bv.x = (kk + 0 < K) ? Bp[kk + 0] : 0.f;
          bv.y = (kk + 1 < K) ? Bp[kk + 1] : 0.f;
          bv.z = (kk + 2 < K) ? Bp[kk + 2] : 0.f;
          bv.w = (kk + 3 < K) ? Bp[kk + 3] : 0.f;
        }
      }
      Bs[kq + 0][rr] = bv.x; Bs[kq + 1][rr] = bv.y;
      Bs[kq + 2][rr] = bv.z; Bs[kq + 3][rr] = bv.w;
    }
    __syncthreads();
#pragma unroll
    for (int k = 0; k < TK; ++k) {
      float a[8], b[8];
      *reinterpret_cast<float4*>(&a[0]) = *reinterpret_cast<const float4*>(&As[k][4 * ty]);
      *reinterpret_cast<float4*>(&a[4]) = *reinterpret_cast<const float4*>(&As[k][64 + 4 * ty]);
      *reinterpret_cast<float4*>(&b[0]) = *reinterpret_cast<const float4*>(&Bs[k][4 * tx]);
      *reinterpret_cast<float4*>(&b[4]) = *reinterpret_cast<const float4*>(&Bs[k][64 + 4 * tx]);
#pragma unroll
      for (int i = 0; i < 8; ++i)
#pragma unroll
        for (int j = 0; j < 8; ++j)
          acc[i][j] = fmaf(a[i], b[j], acc[i][j]);
    }
    __syncthreads();
  }

  if (MODE == 0) {
#pragma unroll
    for (int i = 0; i < 8; ++i) {
      const int ri = r0 + 4 * ty + (i & 3) + (i >> 2) * 64;
      if (ri >= N) continue;
#pragma unroll
      for (int jh = 0; jh < 2; ++jh) {
        float4 v;
        float* vp = reinterpret_cast<float*>(&v);
#pragma unroll
        for (int j = 0; j < 4; ++j) {
          const int cj = c0 + 4 * tx + j + jh * 64;
          vp[j] = (cj < V) ? acc[i][j + jh * 4] : 0.f;
        }
        *reinterpret_cast<float4*>(C + (size_t)ri * ldc + (c0 + 4 * tx + jh * 64)) = v;
      }
    }
  } else {
    float bv[8];
#pragma unroll
    for (int jj = 0; jj < 8; ++jj) {
      const int cj = c0 + 4 * tx + (jj & 3) + (jj >> 2) * 64;
      bv[jj] = (cj < V) ? ((cj < v_split) ? bias1[cj] : bias2[cj - v_split]) : 0.f;
    }
#pragma unroll
    for (int i = 0; i < 8; ++i)
#pragma unroll
      for (int jj = 0; jj < 8; ++jj) {
        const int cj = c0 + 4 * tx + (jj & 3) + (jj >> 2) * 64;
        acc[i][jj] = (cj < V) ? (acc[i][jj] + bv[jj]) : -INFINITY;
      }
#pragma unroll
    for (int i = 0; i < 8; ++i) {
      float m = acc[i][0];
#pragma unroll
      for (int jj = 1; jj < 8; ++jj) m = fmaxf(m, acc[i][jj]);
#pragma unroll
      for (int d = 1; d < 16; d <<= 1) m = fmaxf(m, __shfl_xor(m, d));
      float s = 0.f;
#pragma unroll
      for (int jj = 0; jj < 8; ++jj) s += __expf(acc[i][jj] - m);
#pragma unroll
      for (int d = 1; d < 16; d <<= 1) s += __shfl_xor(s, d);
      const int ri = r0 + 4 * ty + (i & 3) + (i >> 2) * 64;
      if (tx == 0 && ri < nrows) {
        const int orig = rowidx ? rowidx[ri] : ri;
        lse_merge(&lse[orig], m, s);
      }
    }
  }
}

// One wave per token: gathered dot products for the picked logits.
__global__ __launch_bounds__(256)
void pick_kernel(const float* __restrict__ x, const int* __restrict__ tgt,
                 const float* __restrict__ tw0, const float* __restrict__ tb0,
                 const float* __restrict__ cw,  const float* __restrict__ cb,
                 const float* __restrict__ tw1, const float* __restrict__ tb1,
                 const float* __restrict__ tw2, const float* __restrict__ tb2,
                 const float* __restrict__ xt1, const float* __restrict__ xt2,
                 float* __restrict__ pick0, float* __restrict__ pickc,
                 float* __restrict__ pickt, int N)
{
  const int wid  = (blockIdx.x * blockDim.x + threadIdx.x) >> 6;
  const int lane = threadIdx.x & 63;
  if (wid >= N) return;
  const int t = tgt[wid];
  if (t >= 1 && t < CUT1) {
    const float4* xp = reinterpret_cast<const float4*>(x + (size_t)wid * DIM);
    const float4* wp = reinterpret_cast<const float4*>(tw0 + (size_t)t * DIM);
    float s = 0.f;
#pragma unroll
    for (int it = 0; it < DIM / 256; ++it) {
      float4 a = xp[lane + it * 64];
      float4 b = wp[lane + it * 64];
      s += a.x * b.x + a.y * b.y + a.z * b.z + a.w * b.w;
    }
#pragma unroll
    for (int d = 1; d < 64; d <<= 1) s += __shfl_xor(s, d);
    if (lane == 0) pick0[wid] = s + tb0[t];
  } else if (t >= CUT1) {
    const int i2 = (t < CUT2) ? 0 : 1;
    const float4* xp = reinterpret_cast<const float4*>(x + (size_t)wid * DIM);
    const float4* wp = reinterpret_cast<const float4*>(cw + (size_t)i2 * DIM);
    float s = 0.f;
#pragma unroll
    for (int it = 0; it < DIM / 256; ++it) {
      float4 a = xp[lane + it * 64];
      float4 b = wp[lane + it * 64];
      s += a.x * b.x + a.y * b.y + a.z * b.z + a.w * b.w;
    }
#pragma unroll
    for (int d = 1; d < 64; d <<= 1) s += __shfl_xor(s, d);
    const int K  = i2 ? P2 : P1;
    const int ld = i2 ? XT2_LD : XT1_LD;
    const int tj = t - (i2 ? CUT2 : CUT1);
    const float* xr = (i2 ? xt2 : xt1) + (size_t)wid * ld;
    const float* wr = (i2 ? tw2 : tw1) + (size_t)tj * K;
    float s2 = 0.f;
    for (int k = lane; k < K; k += 64) s2 += xr[k] * wr[k];
#pragma unroll
    for (int d = 1; d < 64; d <<= 1) s2 += __shfl_xor(s2, d);
    if (lane == 0) {
      pickc[wid] = s + cb[i2];
      pickt[wid] = s2 + (i2 ? tb2 : tb1)[tj];
    }
  }
}

__global__ void final_kernel(const int* __restrict__ tgt,
                             const unsigned long long* __restrict__ lse,
                             const float* __restrict__ pick0, const float* __restrict__ pickc,
                             const float* __restrict__ pickt,
                             float* __restrict__ out, int N)
{
  const int n = blockIdx.x * blockDim.x + threadIdx.x;
  if (n >= N) return;
  const int t = tgt[n];
  float y = 0.f;
  if (t >= 1 && t < CUT1) {
    unsigned long long p = lse[n];
    float l0 = __uint_as_float((unsigned)(p & 0xffffffffull)) +
               logf(__uint_as_float((unsigned)(p >> 32)));
    y = -(pick0[n] - l0);
  } else if (t >= CUT1) {
    const int i2 = (t < CUT2) ? 0 : 1;
    unsigned long long p = lse[n];
    float l0 = __uint_as_float((unsigned)(p & 0xffffffffull)) +
               logf(__uint_as_float((unsigned)(p >> 32)));
    unsigned long long q = lse[(size_t)(i2 + 1) * N + n];
    float li = __uint_as_float((unsigned)(q & 0xffffffffull)) +
               logf(__uint_as_float((unsigned)(q >> 32)));
    y = -((pickc[n] - l0) + (pickt[n] - li));
  }
  out[n] = y;
}

extern "C" void kernel_launch(void* const* d_in, const int* in_sizes, int n_in,
                              void* d_out, int out_size, void* d_ws, size_t ws_size,
                              hipStream_t stream)
{
  const float* x   = (const float*)d_in[0];
  const int*   tgt = (const int*)d_in[1];
  const float* tw0 = (const float*)d_in[2];
  const float* tb0 = (const float*)d_in[3];
  const float* cw  = (const float*)d_in[4];
  const float* cb  = (const float*)d_in[5];
  const float* tw1 = (const float*)d_in[6];
  const float* tb1 = (const float*)d_in[7];
  const float* aw1 = (const float*)d_in[8];
  const float* tw2 = (const float*)d_in[9];
  const float* tb2 = (const float*)d_in[10];
  const float* aw2 = (const float*)d_in[11];
  float* out = (float*)d_out;
  const int N = in_sizes[1];  // B*S tokens

  // ---- workspace layout ----
  size_t off = 0;
  auto alloc = [&](size_t bytes) { size_t o = off; off += (bytes + 255) & ~(size_t)255; return o; };
  char* ws = (char*)d_ws;
  const size_t o_lse   = alloc((size_t)3 * N * 8);
  const size_t o_part  = alloc((size_t)NSLT * N * 8);
  const size_t o_pick0 = alloc((size_t)N * 4);
  const size_t o_pickc = alloc((size_t)N * 4);
  const size_t o_pickt = alloc((size_t)N * 4);
  const size_t o_cnt   = alloc(2 * 4);
  const size_t o_rows1 = alloc((size_t)N * 4);
  const size_t o_rows2 = alloc((size_t)N * 4);
  const size_t o_xt1   = alloc((size_t)N * XT1_LD * 4);
  const size_t o_xt2   = alloc((size_t)N * XT2_LD * 4);
  const size_t o_xh   = alloc((size_t)N * DIM * 2);
  const size_t o_xl   = alloc((size_t)N * DIM * 2);
  const size_t o_whh  = alloc((size_t)VPAD0 * DIM * 2);
  const size_t o_t1h  = alloc((size_t)VPAD1 * K1P * 2);
  const size_t o_t2h  = alloc((size_t)VPAD2 * K2P * 2);
  const size_t o_a1h  = alloc((size_t)A1R * DIM * 2);
  const size_t o_a1l  = alloc((size_t)A1R * DIM * 2);
  const size_t o_a2h  = alloc((size_t)A2R * DIM * 2);
  const size_t o_a2l  = alloc((size_t)A2R * DIM * 2);
  const size_t o_x1h  = alloc((size_t)N * K1P * 2);
  const size_t o_x2h  = alloc((size_t)N * K2P * 2);
  const size_t need_mfma = off;

  unsigned long long* lse  = (unsigned long long*)(ws + o_lse);
  unsigned long long* part = (unsigned long long*)(ws + o_part);
  float* pick0 = (float*)(ws + o_pick0);
  float* pickc = (float*)(ws + o_pickc);
  float* pickt = (float*)(ws + o_pickt);
  int*   cnt   = (int*)(ws + o_cnt);
  int*   rows1 = (int*)(ws + o_rows1);
  int*   rows2 = (int*)(ws + o_rows2);
  float* xt1   = (float*)(ws + o_xt1);
  float* xt2   = (float*)(ws + o_xt2);

  const int ptot = NSLT * N;
  init_ws<<<dim3((ptot + 255) / 256), dim3(256), 0, stream>>>(lse, 3 * N, part, ptot, cnt);
  build_rows<<<dim3((N + 255) / 256), dim3(256), 0, stream>>>(tgt, cnt, rows1, rows2, N);

  const int rb = (N + 127) / 128;          // 32 row tiles
  const int rpx = (rb + 7) / 8;            // rows per XCD (ROWSHARD)

  if (ws_size >= need_mfma) {
    u16* xh  = (u16*)(ws + o_xh),  *xl  = (u16*)(ws + o_xl);
    u16* whh = (u16*)(ws + o_whh);
    u16* t1h = (u16*)(ws + o_t1h);
    u16* t2h = (u16*)(ws + o_t2h);
    u16* a1h = (u16*)(ws + o_a1h), *a1l = (u16*)(ws + o_a1l);
    u16* a2h = (u16*)(ws + o_a2h), *a2l = (u16*)(ws + o_a2l);
    u16* x1h = (u16*)(ws + o_x1h);
    u16* x2h = (u16*)(ws + o_x2h);

    auto cvt = [&](const float* src, int R, int K, int ldsrc, u16* h, u16* l,
                   int Kpad, int Rpad) {
      const int total = Rpad * (Kpad >> 2);
      cvt_split<<<dim3((total + 255) / 256), 256, 0, stream>>>(src, R, K, ldsrc, h, l, Kpad, total);
    };
    cvt(x,   N,    DIM, DIM, xh, xl, DIM, N);
    cvt(tw0, CUT1, DIM, DIM, whh, nullptr, DIM, CUT1);
    cvt(cw,  2,    DIM, DIM, whh + (size_t)CUT1 * DIM, nullptr, DIM, 96);
    cvt(tw1, CUT2 - CUT1, P1, P1, t1h, nullptr, K1P, VPAD1);
    cvt(tw2, NTOK - CUT2, P2, P2, t2h, nullptr, K2P, VPAD2);
    cvt(aw1, P1, DIM, DIM, a1h, a1l, DIM, A1R);
    cvt(aw2, P2, DIM, DIM, a2h, a2l, DIM, A2R);

    // adapt projections: bf16x3, ROWSHARD
    gemm_mfma<0, 3, 0><<<dim3(8 * rpx * (A1R / 128)), 256, 0, stream>>>(
        xh, xl, DIM, a1h, a1l, DIM, nullptr, nullptr, 0,
        N, A1R, DIM / 32, rb, A1R / 128, rpx, xt1, XT1_LD, nullptr, nullptr, nullptr);
    gemm_mfma<0, 3, 0><<<dim3(8 * rpx * (A2R / 128)), 256, 0, stream>>>(
        xh, xl, DIM, a2h, a2l, DIM, nullptr, nullptr, 0,
        N, A2R, DIM / 32, rb, A2R / 128, rpx, xt2, XT2_LD, nullptr, nullptr, nullptr);
    cvt(xt1, N, K1P, XT1_LD, x1h, nullptr, K1P, N);
    cvt(xt2, N, K2P, XT2_LD, x2h, nullptr, K2P, N);

    // head LSE: pure bf16, ROWSHARD
    gemm_mfma<1, 1, 0><<<dim3(8 * rpx * NCT0), 256, 0, stream>>>(
        xh, nullptr, DIM, whh, nullptr, DIM, tb0, cb, CUT1,
        N, CUT1 + 2, DIM / 32, rb, NCT0, rpx, nullptr, 0, part, nullptr, nullptr);
    // tail1 LSE: pure bf16, COLSHARD, compacted rows
    {
      const int cpx = (NCT1 + 7) / 8;
      gemm_mfma<1, 1, 1><<<dim3(8 * cpx * rb), 256, 0, stream>>>(
          x1h, nullptr, K1P, t1h, nullptr, K1P, tb1, tb1, CUT2 - CUT1,
          N, CUT2 - CUT1, K1P / 32, rb, NCT1, cpx, nullptr, 0,
          part + (size_t)NSL0 * N, rows1, cnt + 0);
    }
    // tail2 LSE
    {
      const int cpx = (NCT2 + 7) / 8;
      gemm_mfma<1, 1, 1><<<dim3(8 * cpx * rb), 256, 0, stream>>>(
          x2h, nullptr, K2P, t2h, nullptr, K2P, tb2, tb2, NTOK - CUT2,
          N, NTOK - CUT2, K2P / 32, rb, NCT2, cpx, nullptr, 0,
          part + (size_t)(NSL0 + NSL1) * N, rows2, cnt + 1);
    }
    // merge partials -> lse[3][N]
    const int rgrid = (N * 64 + 255) / 256;
    reduce_lse<<<dim3(rgrid), 256, 0, stream>>>(part, NSL0, N, lse);
    reduce_lse<<<dim3(rgrid), 256, 0, stream>>>(part + (size_t)NSL0 * N, NSL1, N, lse + N);
    reduce_lse<<<dim3(rgrid), 256, 0, stream>>>(part + (size_t)(NSL0 + NSL1) * N, NSL2, N, lse + 2 * N);
  } else {
    // ---------------- fp32 fallback path ----------------
    gemm_kernel<0><<<dim3(rb, (P1 + TN - 1) / TN), 256, 0, stream>>>(
        x, DIM, aw1, aw1, P1, nullptr, nullptr, N, P1, DIM, xt1, XT1_LD, nullptr,
        nullptr, nullptr);
    gemm_kernel<0><<<dim3(rb, (P2 + TN - 1) / TN), 256, 0, stream>>>(
        x, DIM, aw2, aw2, P2, nullptr, nullptr, N, P2, DIM, xt2, XT2_LD, nullptr,
        nullptr, nullptr);
    gemm_kernel<1><<<dim3(rb, (CUT1 + 2 + TN - 1) / TN), 256, 0, stream>>>(
        x, DIM, tw0, cw, CUT1, tb0, cb, N, CUT1 + 2, DIM, nullptr, 0, lse,
        nullptr, nullptr);
    gemm_kernel<1><<<dim3(rb, (CUT2 - CUT1 + TN - 1) / TN), 256, 0, stream>>>(
        xt1, XT1_LD, tw1, tw1, CUT2 - CUT1, tb1, tb1, N, CUT2 - CUT1, P1, nullptr, 0, lse + N,
        rows1, cnt + 0);
    gemm_kernel<1><<<dim3(rb, (NTOK - CUT2 + TN - 1) / TN), 256, 0, stream>>>(
        xt2, XT2_LD, tw2, tw2, NTOK - CUT2, tb2, tb2, N, NTOK - CUT2, P2, nullptr, 0, lse + 2 * N,
        rows2, cnt + 1);
  }

  pick_kernel<<<dim3((N + 3) / 4), 256, 0, stream>>>(
      x, tgt, tw0, tb0, cw, cb, tw1, tb1, tw2, tb2, xt1, xt2, pick0, pickc, pickt, N);
  final_kernel<<<dim3((N + 255) / 256), 256, 0, stream>>>(
      tgt, lse, pick0, pickc, pickt, out, N);
}